// Round 5
// baseline (185.613 us; speedup 1.0000x reference)
//
#include <hip/hip_runtime.h>
#include <hip/hip_bf16.h>
#include <stdint.h>

// VSN: B=16,T=256 -> NTOK=4096 tokens, V=64 vars, H=256 hidden.
#define NTOK 4096
#define NV 64
#define NH 256
#define LN_EPS 1e-5f

typedef __attribute__((ext_vector_type(8))) short short8;
typedef __attribute__((ext_vector_type(4))) float f32x4;
typedef __attribute__((ext_vector_type(4))) uint32_t u32x4;

__device__ __forceinline__ unsigned short f32_to_bf16(float f) {
    uint32_t u = __builtin_bit_cast(uint32_t, f);
    return (unsigned short)((u + 0x7FFFu + ((u >> 16) & 1u)) >> 16);  // RNE
}
__device__ __forceinline__ float fsigmoid(float z) { return 1.0f / (1.0f + __expf(-z)); }
__device__ __forceinline__ float felu(float z) { return z > 0.0f ? z : (__expf(z) - 1.0f); }
// pack two f32 -> bf16x2 (round-half-up) in 3 ops
__device__ __forceinline__ uint32_t pack_bf16x2(float ze, float zo) {
    const uint32_t ue = __builtin_bit_cast(uint32_t, ze) + 0x8000u;
    const uint32_t uo = __builtin_bit_cast(uint32_t, zo) + 0x8000u;
    return __builtin_amdgcn_perm(uo, ue, 0x07060302u);
}

// ---- Kernel A: W2 [v][h][o] f32 -> W2F fragment-major bf16 ----
// frag(v,ks,f,l)[j] = bf16(W2[v][ks*32+(l>>4)*8+j][f*16+(l&15)]), 16B per (l).
// Layout: W2F[(((v*8+ks)*16+f)*64+l)*8 + j]  (shorts). One block per 32h x 32o tile.
__global__ __launch_bounds__(128) void k_w2f(const float* __restrict__ W2,
                                             unsigned short* __restrict__ W2F) {
    __shared__ float tile[32][36];
    const int v  = blockIdx.x >> 6;
    const int t  = blockIdx.x & 63;
    const int ks = t & 7;
    const int o0 = (t >> 3) * 32;
    const int r  = threadIdx.x >> 2;
    const int c8 = (threadIdx.x & 3) * 8;
    const float* src = W2 + ((size_t)v * NH + ks * 32 + r) * NH + o0 + c8;
    *(float4*)&tile[r][c8]     = *(const float4*)src;
    *(float4*)&tile[r][c8 + 4] = *(const float4*)(src + 4);
    __syncthreads();
    const int fi = threadIdx.x >> 6;           // 0/1
    const int l  = threadIdx.x & 63;
    const int cc = l & 15, kg = l >> 4;
    const int f  = (o0 >> 4) + fi;
    u32x4 w;
#pragma unroll
    for (int p = 0; p < 4; ++p) {
        const float z0 = tile[kg * 8 + 2 * p][fi * 16 + cc];
        const float z1 = tile[kg * 8 + 2 * p + 1][fi * 16 + cc];
        w[p] = (uint32_t)f32_to_bf16(z0) | ((uint32_t)f32_to_bf16(z1) << 16);
    }
    *(u32x4*)(W2F + ((size_t)(((v * 8 + ks) * 16) + f) * 64 + l) * 8) = w;
}

// ---- Kernel A2: x [tok][v] -> xT [v][tok] ----
__global__ __launch_bounds__(256) void k_xt(const float* __restrict__ x,
                                            float* __restrict__ xT) {
    __shared__ float tile[64][65];
    const int t0 = blockIdx.x * 64;
    const int r = threadIdx.x >> 2, q = threadIdx.x & 3;
#pragma unroll
    for (int j = 0; j < 16; ++j)
        tile[r][q * 16 + j] = x[(size_t)(t0 + r) * NV + q * 16 + j];
    __syncthreads();
#pragma unroll
    for (int j = 0; j < 16; ++j)
        xT[(size_t)r * NTOK + t0 + q * 16 + j] = tile[q * 16 + j][r];
}

// ---- Kernel B: weight-network GRN + softmax -> wT[v][tok] (transposed) ----
__global__ __launch_bounds__(256) void k_weights(
    const float* __restrict__ x,
    const float* __restrict__ nW1, const float* __restrict__ nb1,
    const float* __restrict__ nW2, const float* __restrict__ nb2,
    const float* __restrict__ nWg, const float* __restrict__ nbg,
    const float* __restrict__ ng,  const float* __restrict__ nbe,
    float* __restrict__ wT) {
    const int wv = threadIdx.x >> 6;
    const int lane = threadIdx.x & 63;
    const int tok = blockIdx.x * 4 + wv;
    const float xv = x[(size_t)tok * NV + lane];
    float acc1 = nb1[lane], accg = nbg[lane];
#pragma unroll 8
    for (int k = 0; k < 64; ++k) {
        const float xk = __shfl(xv, k);
        acc1 = fmaf(xk, nW1[k * 64 + lane], acc1);
        accg = fmaf(xk, nWg[k * 64 + lane], accg);
    }
    const float h  = felu(acc1);
    const float wg = fsigmoid(accg);
    float acc2 = nb2[lane];
#pragma unroll 8
    for (int k = 0; k < 64; ++k) {
        const float hk = __shfl(h, k);
        acc2 = fmaf(hk, nW2[k * 64 + lane], acc2);
    }
    const float pre = xv + wg * acc2;
    float s = pre;
#pragma unroll
    for (int m = 32; m >= 1; m >>= 1) s += __shfl_xor(s, m);
    const float mu = s * (1.0f / 64.0f);
    const float dd = pre - mu;
    float s2 = dd * dd;
#pragma unroll
    for (int m = 32; m >= 1; m >>= 1) s2 += __shfl_xor(s2, m);
    const float inv = rsqrtf(s2 * (1.0f / 64.0f) + LN_EPS);
    const float wln = dd * inv * ng[lane] + nbe[lane];
    float mx = wln;
#pragma unroll
    for (int m = 32; m >= 1; m >>= 1) mx = fmaxf(mx, __shfl_xor(mx, m));
    const float e = __expf(wln - mx);
    float se = e;
#pragma unroll
    for (int m = 32; m >= 1; m >>= 1) se += __shfl_xor(se, m);
    wT[(size_t)lane * NTOK + tok] = e / se;  // transposed store
}

// ---- Kernel C: barrier-free, LDS-free fused GRN + weighted accumulate ----
// grid 512 (bid&7 = vgroup/XCD; bid>>3 = 64-token tile), 256 thr = 4 fully
// independent waves; wave = 16 tokens x 256 cols. B-frags stream global->VGPR
// (coalesced 1KB dwordx4 from W2F), software-pipelined in half-panels.
#define LOADH(dst, basep, fb)                                               \
    {                                                                       \
        _Pragma("unroll") for (int j_ = 0; j_ < 8; ++j_)                    \
            dst[j_] = *(const u32x4*)((basep) + ((fb) + j_) * 1024 + loff); \
    }

__global__ __launch_bounds__(256, 2) void k_main(
    const char* __restrict__ W2F, const float* __restrict__ xT,
    const float* __restrict__ wT,
    const float* __restrict__ W1, const float* __restrict__ b1,
    const float* __restrict__ Wg, const float* __restrict__ bg,
    const float* __restrict__ Ws, const float* __restrict__ bs,
    const float* __restrict__ b2, const float* __restrict__ g1,
    const float* __restrict__ be1,
    float* __restrict__ partials,   // [8][NTOK][NH] or nullptr
    float* __restrict__ outacc) {   // atomic fallback
    const int tid  = threadIdx.x;
    const int wid  = tid >> 6, lane = tid & 63;
    const int c    = lane & 15, kg = lane >> 4;
    const int vg   = blockIdx.x & 7, tt = blockIdx.x >> 3;
    const int t0   = tt * 64, vbase = vg * 8;
    const int tw   = t0 + wid * 16;          // wave's token base
    const int loff = lane * 16;

    const f32x4 fzero = {0.f, 0.f, 0.f, 0.f};
    f32x4 wacc[16];
#pragma unroll
    for (int f = 0; f < 16; ++f) wacc[f] = fzero;

    u32x4 bLo[8], bHi[8];
    // prologue: half0 of (v=vbase, ks=0)
    const char* pv = W2F + (size_t)vbase * 131072;
    LOADH(bLo, pv, 0);

#pragma unroll 1
    for (int vi = 0; vi < 8; ++vi) {
        const int v = vbase + vi;
        const char* pvn = pv + 131072;
        const float xa = xT[(size_t)v * NTOK + tw + c];
        const float4 xr4 = *(const float4*)&xT[(size_t)v * NTOK + tw + kg * 4];
        const float4 wr4 = *(const float4*)&wT[(size_t)v * NTOK + tw + kg * 4];

        f32x4 acc[16];
#pragma unroll
        for (int f = 0; f < 16; ++f) acc[f] = fzero;

#pragma unroll 1
        for (int ks = 0; ks < 8; ++ks) {
            const char* pk = pv + ks * 16384;
            LOADH(bHi, pk, 8);                        // half1 of current ks
            // A-frag gen
            const float* w1p = W1 + (size_t)v * NH + ks * 32 + kg * 8;
            const float* b1p = b1 + (size_t)v * NH + ks * 32 + kg * 8;
            const float4 wA = *(const float4*)w1p;
            const float4 wB = *(const float4*)(w1p + 4);
            const float4 bA = *(const float4*)b1p;
            const float4 bB = *(const float4*)(b1p + 4);
            u32x4 ap;
            {
                const float z0 = fmaf(xa, wA.x, bA.x), z1 = fmaf(xa, wA.y, bA.y);
                const float z2 = fmaf(xa, wA.z, bA.z), z3 = fmaf(xa, wA.w, bA.w);
                const float z4 = fmaf(xa, wB.x, bB.x), z5 = fmaf(xa, wB.y, bB.y);
                const float z6 = fmaf(xa, wB.z, bB.z), z7 = fmaf(xa, wB.w, bB.w);
                ap[0] = pack_bf16x2(felu(z0), felu(z1));
                ap[1] = pack_bf16x2(felu(z2), felu(z3));
                ap[2] = pack_bf16x2(felu(z4), felu(z5));
                ap[3] = pack_bf16x2(felu(z6), felu(z7));
            }
            const short8 af = __builtin_bit_cast(short8, ap);
            __builtin_amdgcn_s_setprio(1);
#pragma unroll
            for (int f = 0; f < 8; ++f)
                acc[f] = __builtin_amdgcn_mfma_f32_16x16x32_bf16(
                    af, __builtin_bit_cast(short8, bLo[f]), acc[f], 0, 0, 0);
            __builtin_amdgcn_s_setprio(0);
            // prefetch half0 of next ks (or next var's ks0)
            if (ks < 7) {
                LOADH(bLo, pk + 16384, 0);
            } else if (vi < 7) {
                LOADH(bLo, pvn, 0);
            }
            __builtin_amdgcn_s_setprio(1);
#pragma unroll
            for (int f = 0; f < 8; ++f)
                acc[8 + f] = __builtin_amdgcn_mfma_f32_16x16x32_bf16(
                    af, __builtin_bit_cast(short8, bHi[f]), acc[8 + f], 0, 0, 0);
            __builtin_amdgcn_s_setprio(0);
        }
        pv = pvn;

        // ---- epilogue: gate/skip/sigmoid + wave-local LN + weighted accumulate ----
        const float xr[4] = {xr4.x, xr4.y, xr4.z, xr4.w};
        const float wv_[4] = {wr4.x, wr4.y, wr4.z, wr4.w};
        float ps[4] = {}, pq[4] = {};
        const size_t vro = (size_t)v * NH + c;
#pragma unroll
        for (int f = 0; f < 16; ++f) {
            const float Wg_ = Wg[vro + f * 16], bg_ = bg[vro + f * 16];
            const float Ws_ = Ws[vro + f * 16], bs_ = bs[vro + f * 16];
            const float b2_ = b2[vro + f * 16];
#pragma unroll
            for (int r = 0; r < 4; ++r) {
                const float y = fmaf(xr[r], Ws_, bs_) +
                                fsigmoid(fmaf(xr[r], Wg_, bg_)) * (acc[f][r] + b2_);
                acc[f][r] = y;
                ps[r] += y;
                pq[r] = fmaf(y, y, pq[r]);
            }
        }
#pragma unroll
        for (int m = 1; m <= 8; m <<= 1)
#pragma unroll
            for (int r = 0; r < 4; ++r) {
                ps[r] += __shfl_xor(ps[r], m);
                pq[r] += __shfl_xor(pq[r], m);
            }
        float mu[4], wiv[4];
#pragma unroll
        for (int r = 0; r < 4; ++r) {
            mu[r] = ps[r] * (1.0f / 256.0f);
            const float vr = fmaf(-mu[r], mu[r], pq[r] * (1.0f / 256.0f));
            wiv[r] = wv_[r] * rsqrtf(vr + LN_EPS);
        }
#pragma unroll
        for (int f = 0; f < 16; ++f) {
            const float g1_ = g1[vro + f * 16], be_ = be1[vro + f * 16];
#pragma unroll
            for (int r = 0; r < 4; ++r)
                wacc[f][r] = fmaf(wiv[r] * (acc[f][r] - mu[r]), g1_,
                                  fmaf(wv_[r], be_, wacc[f][r]));
        }
    }

    // ---- write per-vgroup partials (or atomic fallback) ----
    const int tokb = t0 + wid * 16 + kg * 4;
    if (partials) {
        float* P = partials + (size_t)vg * NTOK * NH;
#pragma unroll
        for (int r = 0; r < 4; ++r) {
            float* rowp = P + (size_t)(tokb + r) * NH + c;
#pragma unroll
            for (int f = 0; f < 16; ++f) rowp[f * 16] = wacc[f][r];
        }
    } else {
#pragma unroll
        for (int r = 0; r < 4; ++r) {
            float* rowp = outacc + (size_t)(tokb + r) * NH + c;
#pragma unroll
            for (int f = 0; f < 16; ++f) atomicAdd(&rowp[f * 16], wacc[f][r]);
        }
    }
}

// ---- Kernel D: sum the 8 vgroup partials ----
__global__ __launch_bounds__(256) void k_reduce(const float* __restrict__ P,
                                                float* __restrict__ out) {
    const size_t i = ((size_t)blockIdx.x * 256 + threadIdx.x);
    const f32x4* P4 = (const f32x4*)P;
    f32x4 s = P4[i];
#pragma unroll
    for (int sl = 1; sl < 8; ++sl) s += P4[(size_t)sl * (NTOK * NH / 4) + i];
    ((f32x4*)out)[i] = s;
}

extern "C" void kernel_launch(void* const* d_in, const int* in_sizes, int n_in,
                              void* d_out, int out_size, void* d_ws, size_t ws_size,
                              hipStream_t stream) {
    const float* x   = (const float*)d_in[0];
    const float* W1  = (const float*)d_in[1];
    const float* b1  = (const float*)d_in[2];
    const float* W2  = (const float*)d_in[3];
    const float* b2  = (const float*)d_in[4];
    const float* Wg  = (const float*)d_in[5];
    const float* bg  = (const float*)d_in[6];
    const float* Ws  = (const float*)d_in[7];
    const float* bs  = (const float*)d_in[8];
    const float* g1  = (const float*)d_in[9];
    const float* be1 = (const float*)d_in[10];
    const float* nW1 = (const float*)d_in[11];
    const float* nb1 = (const float*)d_in[12];
    const float* nW2 = (const float*)d_in[13];
    const float* nb2 = (const float*)d_in[14];
    const float* nWg = (const float*)d_in[15];
    const float* nbg = (const float*)d_in[16];
    const float* ng  = (const float*)d_in[17];
    const float* nbe = (const float*)d_in[18];
    float* out = (float*)d_out;

    // ws: [0,1M) wT | [1,2M) xT | [2,10M) W2F | [10M,42M) partials
    char* ws = (char*)d_ws;
    float* ws_wT  = (float*)ws;
    float* ws_xT  = (float*)(ws + (1 << 20));
    unsigned short* ws_W2F = (unsigned short*)(ws + (2 << 20));
    const size_t part_off = (size_t)10 << 20;
    const size_t part_bytes = (size_t)8 * NTOK * NH * 4;
    const bool use_part = ws_size >= part_off + part_bytes;
    float* ws_part = use_part ? (float*)(ws + part_off) : nullptr;

    k_w2f<<<dim3(64 * 64), dim3(128), 0, stream>>>(W2, ws_W2F);
    k_xt<<<dim3(NTOK / 64), dim3(256), 0, stream>>>(x, ws_xT);
    k_weights<<<dim3(NTOK / 4), dim3(256), 0, stream>>>(x, nW1, nb1, nW2, nb2,
                                                        nWg, nbg, ng, nbe, ws_wT);
    if (!use_part) hipMemsetAsync(d_out, 0, (size_t)out_size * 4, stream);
    k_main<<<dim3(512), dim3(256), 0, stream>>>((const char*)ws_W2F, ws_xT, ws_wT,
                                                W1, b1, Wg, bg, Ws, bs, b2, g1, be1,
                                                ws_part, out);
    if (use_part)
        k_reduce<<<dim3(NTOK * NH / 4 / 256), dim3(256), 0, stream>>>(ws_part, out);
}

// Round 6
// 172.225 us; speedup vs baseline: 1.0777x; 1.0777x over previous
//
#include <hip/hip_runtime.h>
#include <hip/hip_bf16.h>
#include <stdint.h>

// VSN: B=16,T=256 -> NTOK=4096 tokens, V=64 vars, H=256 hidden.
#define NTOK 4096
#define NV 64
#define NH 256
#define LN_EPS 1e-5f

typedef __attribute__((ext_vector_type(8))) short short8;
typedef __attribute__((ext_vector_type(4))) float f32x4;
typedef __attribute__((ext_vector_type(4))) uint32_t u32x4;

__device__ __forceinline__ unsigned short f32_to_bf16(float f) {
    uint32_t u = __builtin_bit_cast(uint32_t, f);
    return (unsigned short)((u + 0x7FFFu + ((u >> 16) & 1u)) >> 16);  // RNE
}
__device__ __forceinline__ float fsigmoid(float z) { return 1.0f / (1.0f + __expf(-z)); }
__device__ __forceinline__ float felu(float z) { return z > 0.0f ? z : (__expf(z) - 1.0f); }
__device__ __forceinline__ uint32_t pack_bf16x2(float ze, float zo) {
    const uint32_t ue = __builtin_bit_cast(uint32_t, ze) + 0x8000u;
    const uint32_t uo = __builtin_bit_cast(uint32_t, zo) + 0x8000u;
    return __builtin_amdgcn_perm(uo, ue, 0x07060302u);
}
__device__ __forceinline__ void gload16(const void* g, void* l) {
    __builtin_amdgcn_global_load_lds(
        (const __attribute__((address_space(1))) uint32_t*)g,
        (__attribute__((address_space(3))) uint32_t*)l, 16, 0, 0);
}

// ---- Kernel A: W2 [v][h][o] f32 -> W2F fragment-major bf16 ----
// frag(v,ks,f,l)[j] = bf16(W2[v][ks*32+(l>>4)*8+j][f*16+(l&15)]); 16KB per (v,ks).
__global__ __launch_bounds__(128) void k_w2f(const float* __restrict__ W2,
                                             unsigned short* __restrict__ W2F) {
    __shared__ float tile[32][36];
    const int v  = blockIdx.x >> 6;
    const int t  = blockIdx.x & 63;
    const int ks = t & 7;
    const int o0 = (t >> 3) * 32;
    const int r  = threadIdx.x >> 2;
    const int c8 = (threadIdx.x & 3) * 8;
    const float* src = W2 + ((size_t)v * NH + ks * 32 + r) * NH + o0 + c8;
    *(float4*)&tile[r][c8]     = *(const float4*)src;
    *(float4*)&tile[r][c8 + 4] = *(const float4*)(src + 4);
    __syncthreads();
    const int fi = threadIdx.x >> 6;           // 0/1
    const int l  = threadIdx.x & 63;
    const int cc = l & 15, kg = l >> 4;
    const int f  = (o0 >> 4) + fi;
    u32x4 w;
#pragma unroll
    for (int p = 0; p < 4; ++p) {
        const float z0 = tile[kg * 8 + 2 * p][fi * 16 + cc];
        const float z1 = tile[kg * 8 + 2 * p + 1][fi * 16 + cc];
        w[p] = (uint32_t)f32_to_bf16(z0) | ((uint32_t)f32_to_bf16(z1) << 16);
    }
    *(u32x4*)(W2F + ((size_t)(((v * 8 + ks) * 16) + f) * 64 + l) * 8) = w;
}

// ---- Kernel A2: x [tok][v] -> xT [v][tok] ----
__global__ __launch_bounds__(256) void k_xt(const float* __restrict__ x,
                                            float* __restrict__ xT) {
    __shared__ float tile[64][65];
    const int t0 = blockIdx.x * 64;
    const int r = threadIdx.x >> 2, q = threadIdx.x & 3;
#pragma unroll
    for (int j = 0; j < 16; ++j)
        tile[r][q * 16 + j] = x[(size_t)(t0 + r) * NV + q * 16 + j];
    __syncthreads();
#pragma unroll
    for (int j = 0; j < 16; ++j)
        xT[(size_t)r * NTOK + t0 + q * 16 + j] = tile[q * 16 + j][r];
}

// ---- Kernel B: weight-network GRN + softmax -> wT[v][tok] ----
__global__ __launch_bounds__(256) void k_weights(
    const float* __restrict__ x,
    const float* __restrict__ nW1, const float* __restrict__ nb1,
    const float* __restrict__ nW2, const float* __restrict__ nb2,
    const float* __restrict__ nWg, const float* __restrict__ nbg,
    const float* __restrict__ ng,  const float* __restrict__ nbe,
    float* __restrict__ wT) {
    const int wv = threadIdx.x >> 6;
    const int lane = threadIdx.x & 63;
    const int tok = blockIdx.x * 4 + wv;
    const float xv = x[(size_t)tok * NV + lane];
    float acc1 = nb1[lane], accg = nbg[lane];
#pragma unroll 8
    for (int k = 0; k < 64; ++k) {
        const float xk = __shfl(xv, k);
        acc1 = fmaf(xk, nW1[k * 64 + lane], acc1);
        accg = fmaf(xk, nWg[k * 64 + lane], accg);
    }
    const float h  = felu(acc1);
    const float wg = fsigmoid(accg);
    float acc2 = nb2[lane];
#pragma unroll 8
    for (int k = 0; k < 64; ++k) {
        const float hk = __shfl(h, k);
        acc2 = fmaf(hk, nW2[k * 64 + lane], acc2);
    }
    const float pre = xv + wg * acc2;
    float s = pre;
#pragma unroll
    for (int m = 32; m >= 1; m >>= 1) s += __shfl_xor(s, m);
    const float mu = s * (1.0f / 64.0f);
    const float dd = pre - mu;
    float s2 = dd * dd;
#pragma unroll
    for (int m = 32; m >= 1; m >>= 1) s2 += __shfl_xor(s2, m);
    const float inv = rsqrtf(s2 * (1.0f / 64.0f) + LN_EPS);
    const float wln = dd * inv * ng[lane] + nbe[lane];
    float mx = wln;
#pragma unroll
    for (int m = 32; m >= 1; m >>= 1) mx = fmaxf(mx, __shfl_xor(mx, m));
    const float e = __expf(wln - mx);
    float se = e;
#pragma unroll
    for (int m = 32; m >= 1; m >>= 1) se += __shfl_xor(se, m);
    wT[(size_t)lane * NTOK + tok] = e / se;
}

// ---- Kernel C: K-split 8-wave fused GRN + weighted accumulate ----
// grid 512 (bid&7 = vgroup/XCD; bid>>3 = 64-token tile). 512 thr = 8 waves =
// 4 token-groups x 2 K-halves (kh0: ks0-3, kh1: ks4-7). 4096 waves total ->
// 16 waves/CU = 4/SIMD (needs VGPR<=128: LDS staging, wacc[8], lb(512,4)).
// Per var: 4 staged phases (2 panels each, dbuf), acc-exchange via LDS,
// epilogue split by f-half across the kh pair.
__global__ __launch_bounds__(512, 4) void k_main(
    const char* __restrict__ W2F, const float* __restrict__ xT,
    const float* __restrict__ wT,
    const float* __restrict__ W1, const float* __restrict__ b1,
    const float* __restrict__ Wg, const float* __restrict__ bg,
    const float* __restrict__ Ws, const float* __restrict__ bs,
    const float* __restrict__ b2, const float* __restrict__ g1,
    const float* __restrict__ be1,
    float* __restrict__ partials,   // [8][NTOK][NH] or nullptr
    float* __restrict__ outacc) {
    __shared__ __align__(16) char sP[65536];   // 2 bufs x 2 kh x 16KB panels
    __shared__ float sLN[4][16][2][2];         // [tg][tokrow][kh][ps,pq]

    const int tid = threadIdx.x;
    const int wid = tid >> 6, lane = tid & 63;
    const int c = lane & 15, kg = lane >> 4;
    const int tg = wid >> 1, kh = wid & 1;
    const int vg = blockIdx.x & 7, tt = blockIdx.x >> 3;
    const int t0 = tt * 64, vbase = vg * 8;
    const int tw = t0 + tg * 16;

    // prologue: stage v0 panels (ks0 -> kh0 slot, ks4 -> kh1 slot) into buf0
    {
        const char* base = W2F + (size_t)vbase * 131072;
#pragma unroll
        for (int q = 0; q < 4; ++q) {
            const int chunk = q * 512 + tid;
            const int khp = chunk >> 10, off = (chunk & 1023) * 16;
            gload16(base + (size_t)(khp * 4) * 16384 + off, sP + khp * 16384 + off);
        }
    }
    __syncthreads();

    const f32x4 fzero = {0.f, 0.f, 0.f, 0.f};
    f32x4 wacc[8];
#pragma unroll
    for (int f = 0; f < 8; ++f) wacc[f] = fzero;

#pragma unroll 1
    for (int vi = 0; vi < 8; ++vi) {
        const int v = vbase + vi;
        const float xa = xT[(size_t)v * NTOK + tw + c];

        f32x4 acc[16];
#pragma unroll
        for (int f = 0; f < 16; ++f) acc[f] = fzero;

#pragma unroll 1
        for (int p = 0; p < 4; ++p) {
            const int cur = p & 1, nxt = cur ^ 1;
            // stage next phase's 2 panels (p<3: ks p+1/p+5; p==3: next var ks0/ks4)
            if (p < 3 || vi < 7) {
                const char* base = W2F + (size_t)(v + (p == 3 ? 1 : 0)) * 131072;
                const int ksn = (p == 3) ? 0 : (p + 1);
#pragma unroll
                for (int q = 0; q < 4; ++q) {
                    const int chunk = q * 512 + tid;
                    const int khp = chunk >> 10, off = (chunk & 1023) * 16;
                    gload16(base + (size_t)(ksn + khp * 4) * 16384 + off,
                            sP + nxt * 32768 + khp * 16384 + off);
                }
            }
            // A-gen for this wave's ks
            const int ks = p + kh * 4;
            const float* w1p = W1 + (size_t)v * NH + ks * 32 + kg * 8;
            const float* b1p = b1 + (size_t)v * NH + ks * 32 + kg * 8;
            const float4 wA = *(const float4*)w1p;
            const float4 wB = *(const float4*)(w1p + 4);
            const float4 bA = *(const float4*)b1p;
            const float4 bB = *(const float4*)(b1p + 4);
            u32x4 ap;
            {
                const float z0 = fmaf(xa, wA.x, bA.x), z1 = fmaf(xa, wA.y, bA.y);
                const float z2 = fmaf(xa, wA.z, bA.z), z3 = fmaf(xa, wA.w, bA.w);
                const float z4 = fmaf(xa, wB.x, bB.x), z5 = fmaf(xa, wB.y, bB.y);
                const float z6 = fmaf(xa, wB.z, bB.z), z7 = fmaf(xa, wB.w, bB.w);
                ap[0] = pack_bf16x2(felu(z0), felu(z1));
                ap[1] = pack_bf16x2(felu(z2), felu(z3));
                ap[2] = pack_bf16x2(felu(z4), felu(z5));
                ap[3] = pack_bf16x2(felu(z6), felu(z7));
            }
            const short8 af = __builtin_bit_cast(short8, ap);
            const char* bb = sP + cur * 32768 + kh * 16384 + lane * 16;
            __builtin_amdgcn_s_setprio(1);
#pragma unroll
            for (int f = 0; f < 16; ++f) {
                const short8 bf = __builtin_bit_cast(short8, *(const u32x4*)(bb + (f << 10)));
                acc[f] = __builtin_amdgcn_mfma_f32_16x16x32_bf16(af, bf, acc[f], 0, 0, 0);
            }
            __builtin_amdgcn_s_setprio(0);
            __syncthreads();   // drains stage + buffer swap
        }
        // ---- cross-kh acc exchange (aliases buf1 = just-consumed p3 panels) ----
        char* xch = sP + 32768 + tg * 8192 + lane * 16;
        if (kh == 1) {
#pragma unroll
            for (int f = 0; f < 8; ++f) *(f32x4*)(xch + (f << 10)) = acc[f];
        }
        __syncthreads();
        if (kh == 0) {
#pragma unroll
            for (int f = 0; f < 8; ++f) acc[f] += *(const f32x4*)(xch + (f << 10));
#pragma unroll
            for (int f = 0; f < 8; ++f) *(f32x4*)(xch + (f << 10)) = acc[8 + f];
        }
        __syncthreads();
        if (kh == 1) {
#pragma unroll
            for (int f = 0; f < 8; ++f)
                acc[f] = acc[8 + f] + *(const f32x4*)(xch + (f << 10));
        }
        // ---- epilogue on this wave's f-half (acc[0..7] now full-K sums) ----
        const float4 xr4 = *(const float4*)&xT[(size_t)v * NTOK + tw + kg * 4];
        const float xr[4] = {xr4.x, xr4.y, xr4.z, xr4.w};
        float ps[4] = {}, pq[4] = {};
        const size_t vro = (size_t)v * NH + kh * 128 + c;
#pragma unroll
        for (int f = 0; f < 8; ++f) {
            const float Wg_ = Wg[vro + f * 16], bg_ = bg[vro + f * 16];
            const float Ws_ = Ws[vro + f * 16], bs_ = bs[vro + f * 16];
            const float b2_ = b2[vro + f * 16];
#pragma unroll
            for (int r = 0; r < 4; ++r) {
                const float y = fmaf(xr[r], Ws_, bs_) +
                                fsigmoid(fmaf(xr[r], Wg_, bg_)) * (acc[f][r] + b2_);
                acc[f][r] = y;
                ps[r] += y;
                pq[r] = fmaf(y, y, pq[r]);
            }
        }
#pragma unroll
        for (int m = 1; m <= 8; m <<= 1)
#pragma unroll
            for (int r = 0; r < 4; ++r) {
                ps[r] += __shfl_xor(ps[r], m);
                pq[r] += __shfl_xor(pq[r], m);
            }
        if (c == 0) {
#pragma unroll
            for (int r = 0; r < 4; ++r)
                *(float2*)&sLN[tg][kg * 4 + r][kh][0] = float2{ps[r], pq[r]};
        }
        __syncthreads();   // sLN ready; also fences xch reads before restage
        const float4 wr4 = *(const float4*)&wT[(size_t)v * NTOK + tw + kg * 4];
        const float wv_[4] = {wr4.x, wr4.y, wr4.z, wr4.w};
        float mu[4], wiv[4];
#pragma unroll
        for (int r = 0; r < 4; ++r) {
            const float2 a = *(const float2*)&sLN[tg][kg * 4 + r][0][0];
            const float2 bq = *(const float2*)&sLN[tg][kg * 4 + r][1][0];
            mu[r] = (a.x + bq.x) * (1.0f / 256.0f);
            const float vr = fmaf(-mu[r], mu[r], (a.y + bq.y) * (1.0f / 256.0f));
            wiv[r] = wv_[r] * rsqrtf(vr + LN_EPS);
        }
#pragma unroll
        for (int f = 0; f < 8; ++f) {
            const float g1_ = g1[vro + f * 16], be_ = be1[vro + f * 16];
#pragma unroll
            for (int r = 0; r < 4; ++r)
                wacc[f][r] = fmaf(wiv[r] * (acc[f][r] - mu[r]), g1_,
                                  fmaf(wv_[r], be_, wacc[f][r]));
        }
    }

    // ---- write per-vgroup partials (this wave's f-half) ----
    const int tokb = t0 + tg * 16 + kg * 4;
    const int hbase = kh * 128 + c;
    if (partials) {
        float* P = partials + (size_t)vg * NTOK * NH;
#pragma unroll
        for (int r = 0; r < 4; ++r) {
            float* rowp = P + (size_t)(tokb + r) * NH + hbase;
#pragma unroll
            for (int f = 0; f < 8; ++f) rowp[f * 16] = wacc[f][r];
        }
    } else {
#pragma unroll
        for (int r = 0; r < 4; ++r) {
            float* rowp = outacc + (size_t)(tokb + r) * NH + hbase;
#pragma unroll
            for (int f = 0; f < 8; ++f) atomicAdd(&rowp[f * 16], wacc[f][r]);
        }
    }
}

// ---- Kernel D: sum the 8 vgroup partials ----
__global__ __launch_bounds__(256) void k_reduce(const float* __restrict__ P,
                                                float* __restrict__ out) {
    const size_t i = ((size_t)blockIdx.x * 256 + threadIdx.x);
    const f32x4* P4 = (const f32x4*)P;
    f32x4 s = P4[i];
#pragma unroll
    for (int sl = 1; sl < 8; ++sl) s += P4[(size_t)sl * (NTOK * NH / 4) + i];
    ((f32x4*)out)[i] = s;
}

extern "C" void kernel_launch(void* const* d_in, const int* in_sizes, int n_in,
                              void* d_out, int out_size, void* d_ws, size_t ws_size,
                              hipStream_t stream) {
    const float* x   = (const float*)d_in[0];
    const float* W1  = (const float*)d_in[1];
    const float* b1  = (const float*)d_in[2];
    const float* W2  = (const float*)d_in[3];
    const float* b2  = (const float*)d_in[4];
    const float* Wg  = (const float*)d_in[5];
    const float* bg  = (const float*)d_in[6];
    const float* Ws  = (const float*)d_in[7];
    const float* bs  = (const float*)d_in[8];
    const float* g1  = (const float*)d_in[9];
    const float* be1 = (const float*)d_in[10];
    const float* nW1 = (const float*)d_in[11];
    const float* nb1 = (const float*)d_in[12];
    const float* nW2 = (const float*)d_in[13];
    const float* nb2 = (const float*)d_in[14];
    const float* nWg = (const float*)d_in[15];
    const float* nbg = (const float*)d_in[16];
    const float* ng  = (const float*)d_in[17];
    const float* nbe = (const float*)d_in[18];
    float* out = (float*)d_out;

    // ws: [0,1M) wT | [1,2M) xT | [2,10M) W2F | [10M,42M) partials
    char* ws = (char*)d_ws;
    float* ws_wT  = (float*)ws;
    float* ws_xT  = (float*)(ws + (1 << 20));
    unsigned short* ws_W2F = (unsigned short*)(ws + (2 << 20));
    const size_t part_off = (size_t)10 << 20;
    const size_t part_bytes = (size_t)8 * NTOK * NH * 4;
    const bool use_part = ws_size >= part_off + part_bytes;
    float* ws_part = use_part ? (float*)(ws + part_off) : nullptr;

    k_w2f<<<dim3(64 * 64), dim3(128), 0, stream>>>(W2, ws_W2F);
    k_xt<<<dim3(NTOK / 64), dim3(256), 0, stream>>>(x, ws_xT);
    k_weights<<<dim3(NTOK / 4), dim3(256), 0, stream>>>(x, nW1, nb1, nW2, nb2,
                                                        nWg, nbg, ng, nbe, ws_wT);
    if (!use_part) hipMemsetAsync(d_out, 0, (size_t)out_size * 4, stream);
    k_main<<<dim3(512), dim3(512), 0, stream>>>((const char*)ws_W2F, ws_xT, ws_wT,
                                                W1, b1, Wg, bg, Ws, bs, b2, g1, be1,
                                                ws_part, out);
    if (use_part)
        k_reduce<<<dim3(NTOK * NH / 4 / 256), dim3(256), 0, stream>>>(ws_part, out);
}